// Round 4
// baseline (274.710 us; speedup 1.0000x reference)
//
#include <hip/hip_runtime.h>
#include <cmath>

#define NA 3
#define HSIZE 8192
#define HMASK (HSIZE - 1)

typedef float v4f __attribute__((ext_vector_type(4)));

// ws layout:
//   0:      double sums[16]     [0]=nb_dense [1]=conf_dense [2]=c50_dense
//                               [3]=excl_nb [4]=excl_conf [5]=excl_cnt
//                               [6..9]=lx,ly,lw,lh [10]=bce_obj [11]=conf_obj
//                               [12]=i50det [13]=i75det [14]=n_obj
//   128:    int A_key[8192]  A_val[8192]  B_key[8192]  B_bits[8192]  B_maxt[8192]
//   then:   int ocell[T]  keyarr[T]

__device__ __forceinline__ float sigf(float v){ return 1.0f/(1.0f + expf(-v)); }
__device__ __forceinline__ unsigned hslot(unsigned key){
  return (key * 2654435761u) >> 19;   // top 13 bits -> [0, 8192)
}

__global__ __launch_bounds__(256) void k_zero(int* __restrict__ p, int n){
  int i = blockIdx.x*256 + threadIdx.x;
  if (i < n) p[i] = 0;
}

__global__ __launch_bounds__(256) void k_targets(
    const float* __restrict__ targets, int T, int G, float stride,
    int* __restrict__ ocell, int* __restrict__ keyarr,
    int* __restrict__ A_key, int* __restrict__ A_val,
    int* __restrict__ B_key, int* __restrict__ B_bits, int* __restrict__ B_maxt)
{
  int t = blockIdx.x*256 + threadIdx.x;
  if (t >= T) return;
  const float* tr = targets + (size_t)t*6;
  int b = (int)tr[0];
  float gx = tr[2]*(float)G, gy = tr[3]*(float)G, gw = tr[4]*(float)G, gh = tr[5]*(float)G;
  float aw[NA] = {116.0f/stride, 156.0f/stride, 373.0f/stride};
  float ah[NA] = { 90.0f/stride, 198.0f/stride, 326.0f/stride};
  float best_iou = -1.0f; int best = 0; int bits = 0;
  #pragma unroll
  for (int a = 0; a < NA; ++a){
    float inter = fminf(aw[a], gw) * fminf(ah[a], gh);
    float uni   = aw[a]*ah[a] + gw*gh - inter;
    float iou   = inter / (uni + 1e-16f);
    if (iou > best_iou){ best_iou = iou; best = a; }
    if (iou > 0.5f) bits |= (1 << a);
  }
  bits |= (1 << best);
  int gi = (int)floorf(gx); gi = gi < 0 ? 0 : (gi > G-1 ? G-1 : gi);
  int gj = (int)floorf(gy); gj = gj < 0 ? 0 : (gj > G-1 ? G-1 : gj);
  int cell = (b*G + gj)*G + gi;             // < 2^21
  int okey = cell*4 + best;
  ocell[t]  = okey;
  keyarr[t] = (cell << 3) | bits;

  // table A: (cell,best) -> max t (last target wins scatter semantics)
  unsigned s = hslot((unsigned)okey) & HMASK;
  for (;;){
    int prev = atomicCAS(&A_key[s], 0, okey+1);
    if (prev == 0 || prev == okey+1){ atomicMax(&A_val[s], t+1); break; }
    s = (s+1) & HMASK;
  }
  // table B: cell -> union of excluded anchor bits, representative = max t
  s = hslot((unsigned)cell) & HMASK;
  for (;;){
    int prev = atomicCAS(&B_key[s], 0, cell+1);
    if (prev == 0 || prev == cell+1){
      atomicOr(&B_bits[s], bits);
      atomicMax(&B_maxt[s], t+1);
      break;
    }
    s = (s+1) & HMASK;
  }
}

__global__ __launch_bounds__(256) void k_sparse(
    const float* __restrict__ x, const float* __restrict__ targets,
    int T, int G, float stride,
    const int* __restrict__ ocell, const int* __restrict__ keyarr,
    const int* __restrict__ A_key, const int* __restrict__ A_val,
    const int* __restrict__ B_key, const int* __restrict__ B_bits,
    const int* __restrict__ B_maxt, double* __restrict__ sums)
{
  int tid = threadIdx.x;
  int t = blockIdx.x*256 + tid;
  double v[12];
  #pragma unroll
  for (int k = 0; k < 12; ++k) v[k] = 0.0;
  // v: [0]=excl_nb [1]=excl_conf [2]=excl_cnt [3..6]=lx,ly,lw,lh
  //    [7]=bce [8]=conf_obj [9]=i50 [10]=i75 [11]=n_obj

  if (t < T){
    const float* tr = targets + (size_t)t*6;
    int b = (int)tr[0];
    float gx = tr[2]*(float)G, gy = tr[3]*(float)G, gw = tr[4]*(float)G, gh = tr[5]*(float)G;
    float aw[NA] = {116.0f/stride, 156.0f/stride, 373.0f/stride};
    float ah[NA] = { 90.0f/stride, 198.0f/stride, 326.0f/stride};
    int okey = ocell[t];
    int myk  = keyarr[t];
    int cell = myk >> 3;
    int best = okey & 3;
    int gi = cell % G;
    int gj = (cell / G) % G;
    int GG = G*G;

    // ownership lookup (last target wins)
    unsigned s = hslot((unsigned)okey) & HMASK;
    while (A_key[s] != okey+1) s = (s+1) & HMASK;
    bool owner = (A_val[s] == t+1);

    if (owner){
      float awb = aw[best], ahb = ah[best];
      const float* xp = x + ((size_t)(b*(NA*5) + best*5))*GG + (size_t)gj*G + gi;
      float x0 = xp[0], x1 = xp[(size_t)GG], x2 = xp[(size_t)2*GG],
            x3 = xp[(size_t)3*GG], x4 = xp[(size_t)4*GG];
      float cx = sigf(x0), cy = sigf(x1), w = x2, h = x3, conf = sigf(x4);
      float tx = gx - (float)gi, ty = gy - (float)gj;
      float tw = logf(gw/awb + 1e-16f), th = logf(gh/ahb + 1e-16f);
      v[3] = (double)((cx-tx)*(cx-tx));
      v[4] = (double)((cy-ty)*(cy-ty));
      v[5] = (double)((w-tw)*(w-tw));
      v[6] = (double)((h-th)*(h-th));
      v[7] = (double)(-logf(conf + 1e-12f));
      v[8] = (double)conf;
      float px = (float)gi + cx, py = (float)gj + cy;
      float pw = expf(w)*awb, ph = expf(h)*ahb;
      float iw = fminf(px + pw*0.5f, gx + gw*0.5f) - fmaxf(px - pw*0.5f, gx - gw*0.5f);
      float ih = fminf(py + ph*0.5f, gy + gh*0.5f) - fmaxf(py - ph*0.5f, gy - gh*0.5f);
      iw = fmaxf(iw, 0.0f); ih = fmaxf(ih, 0.0f);
      float inter = iw*ih;
      float iou = inter / (pw*ph + gw*gh - inter + 1e-16f);
      bool det = conf > 0.5f;
      v[9]  = (iou > 0.5f  && det) ? 1.0 : 0.0;
      v[10] = (iou > 0.75f && det) ? 1.0 : 0.0;
      v[11] = 1.0;
    }

    // exclusion: representative per distinct cell processes the bit union
    s = hslot((unsigned)cell) & HMASK;
    while (B_key[s] != cell+1) s = (s+1) & HMASK;
    if (B_maxt[s] == t+1){
      int bits = B_bits[s];
      #pragma unroll
      for (int a = 0; a < NA; ++a){
        if (bits & (1 << a)){
          float x4 = x[((size_t)(b*(NA*5) + a*5 + 4))*GG + (size_t)gj*G + gi];
          float conf = sigf(x4);
          v[0] += (double)(-logf(1.0f - conf + 1e-12f));
          v[1] += (double)conf;
          v[2] += 1.0;
        }
      }
    }
  }

  // wave shuffle reduce, then 4 wave-partials in LDS, then atomics
  #pragma unroll
  for (int k = 0; k < 12; ++k){
    #pragma unroll
    for (int off = 32; off > 0; off >>= 1) v[k] += __shfl_down(v[k], off);
  }
  __shared__ double sred[4][12];
  int lane = tid & 63, wv = tid >> 6;
  if (lane == 0){
    #pragma unroll
    for (int k = 0; k < 12; ++k) sred[wv][k] = v[k];
  }
  __syncthreads();
  if (tid < 12){
    double sm = sred[0][tid] + sred[1][tid] + sred[2][tid] + sred[3][tid];
    unsafeAtomicAdd(&sums[3 + tid], sm);
  }
}

// 4 cells/thread. Planar coalesced loads -> compute -> LDS (stride-21 floats,
// 2-way-free banks) -> per-wave 5x fully-coalesced 1KB nontemporal stores.
// LDS 21.5KB -> 7 blocks/CU.
__global__ __launch_bounds__(256) void k_dense(
    const float* __restrict__ x, float* __restrict__ out,
    double* __restrict__ sums, int G, float stride, int total_cells)
{
  __shared__ float lds[256*21];   // 21504 B
  int tid = threadIdx.x;
  int i = blockIdx.x*256 + tid;
  int cell = i*4;
  double nb = 0.0, cs = 0.0;
  int c50i = 0;

  if (cell < total_cells){
    int GG = G*G;
    int gx    = cell % G;           // multiple of 4
    int row   = cell / G;
    int gy    = row % G;
    int plane = row / G;            // b*3 + a
    int a     = plane % NA;
    float aw_all[NA] = {116.0f/stride, 156.0f/stride, 373.0f/stride};
    float ah_all[NA] = { 90.0f/stride, 198.0f/stride, 326.0f/stride};
    float aw = aw_all[a], ah = ah_all[a];

    size_t base = (size_t)plane*5*GG + (size_t)gy*G + gx;
    v4f v[5];
    #pragma unroll
    for (int c = 0; c < 5; ++c)
      v[c] = *(const v4f*)(x + base + (size_t)c*GG);

    float* myl = lds + tid*21;
    #pragma unroll
    for (int j = 0; j < 4; ++j){
      float p0 = v[0][j];
      float p1 = v[1][j];
      float p2 = v[2][j];
      float p3 = v[3][j];
      float p4 = v[4][j];
      float cx   = 1.0f/(1.0f + expf(-p0));
      float cy   = 1.0f/(1.0f + expf(-p1));
      float pw   = expf(p2)*aw;
      float ph   = expf(p3)*ah;
      float conf = 1.0f/(1.0f + expf(-p4));
      myl[j*5+0] = ((float)(gx + j) + cx)*stride;
      myl[j*5+1] = ((float)gy + cy)*stride;
      myl[j*5+2] = pw*stride;
      myl[j*5+3] = ph*stride;
      myl[j*5+4] = conf;
      nb += (double)(-logf(1.0f - conf + 1e-12f));
      cs += (double)conf;
      c50i += (conf > 0.5f) ? 1 : 0;
    }
  }
  __syncthreads();

  // store phase: wave wv owns output floats [waveBase, waveBase+1280)
  int lane = tid & 63, wv = tid >> 6;
  {
    size_t waveBase = ((size_t)blockIdx.x*1024 + (size_t)wv*256)*5;
    if (waveBase < (size_t)total_cells*5){
      const float* wl = lds + (size_t)(wv*64)*21;
      #pragma unroll
      for (int c = 0; c < 5; ++c){
        int f = (c*64 + lane)*4;        // [0, 1280), multiple of 4
        int owner = f / 20;
        int within = f - owner*20;      // in {0,4,8,12,16} -> stays inside owner's 20
        const float* src = wl + owner*21 + within;
        v4f val;
        val.x = src[0]; val.y = src[1]; val.z = src[2]; val.w = src[3];
        __builtin_nontemporal_store(val, (v4f*)(out + waveBase + f));
      }
    }
  }

  double vals[3] = {nb, cs, (double)c50i};
  #pragma unroll
  for (int k = 0; k < 3; ++k){
    #pragma unroll
    for (int off = 32; off > 0; off >>= 1) vals[k] += __shfl_down(vals[k], off);
  }
  __shared__ double sred[4][3];
  if (lane == 0){
    sred[wv][0] = vals[0]; sred[wv][1] = vals[1]; sred[wv][2] = vals[2];
  }
  __syncthreads();
  if (tid < 3){
    double sm = sred[0][tid] + sred[1][tid] + sred[2][tid] + sred[3][tid];
    unsafeAtomicAdd(&sums[tid], sm);
  }
}

__global__ __launch_bounds__(64) void k_final(
    const double* __restrict__ sums, float* __restrict__ tail, double total_cells)
{
  if (threadIdx.x != 0) return;
  double nb_all = sums[0], conf_all = sums[1], c50_all = sums[2];
  double enb = sums[3], econf = sums[4], ecnt = sums[5];
  double lx = sums[6], ly = sums[7], lw = sums[8], lh = sums[9];
  double bce = sums[10], cobj = sums[11], i50 = sums[12], i75 = sums[13], nobj = sums[14];

  double dObj = fmax(nobj, 1.0);
  double n_noobj = total_cells - ecnt;
  double dNo  = fmax(n_noobj, 1.0);

  double loss_x = lx/dObj, loss_y = ly/dObj, loss_w = lw/dObj, loss_h = lh/dObj;
  double loss_bbox = loss_x + loss_y + loss_w + loss_h;
  double loss_conf_obj   = bce/dObj;
  double loss_conf_noobj = (nb_all - enb)/dNo;
  double loss_conf  = 100.0*loss_conf_obj + 1.0*loss_conf_noobj;
  double loss_layer = loss_bbox + loss_conf;
  double conf_obj   = cobj/dObj;
  double conf_noobj = (conf_all - econf)/dNo;
  double precision  = i50/(c50_all + 1e-16);
  double recall50   = i50/(nobj + 1e-16);
  double recall75   = i75/(nobj + 1e-16);

  tail[0]  = (float)loss_layer;
  tail[1]  = (float)loss_x;
  tail[2]  = (float)loss_y;
  tail[3]  = (float)loss_w;
  tail[4]  = (float)loss_h;
  tail[5]  = (float)loss_bbox;
  tail[6]  = (float)loss_conf;
  tail[7]  = (float)loss_layer;
  tail[8]  = (float)conf_obj;
  tail[9]  = (float)conf_noobj;
  tail[10] = (float)precision;
  tail[11] = (float)recall50;
  tail[12] = (float)recall75;
}

extern "C" void kernel_launch(void* const* d_in, const int* in_sizes, int n_in,
                              void* d_out, int out_size, void* d_ws, size_t ws_size,
                              hipStream_t stream) {
  const float* x       = (const float*)d_in[0];
  const float* targets = (const float*)d_in[1];
  float* out = (float*)d_out;

  const int B = 32;
  int GG = in_sizes[0] / (B * NA * 5);
  int G = (int)(sqrt((double)GG) + 0.5);
  int T = in_sizes[1] / 6;
  float stride = 2048.0f / (float)G;

  char* ws = (char*)d_ws;
  double* sums  = (double*)ws;
  int* A_key  = (int*)(ws + 128);
  int* A_val  = A_key + HSIZE;
  int* B_key  = A_val + HSIZE;
  int* B_bits = B_key + HSIZE;
  int* B_maxt = B_bits + HSIZE;
  int* ocell  = B_maxt + HSIZE;
  int* keyarr = ocell + T;

  int total_cells = B * NA * GG;            // 6,291,456
  int nzero = 32 + 5*HSIZE;                 // sums (as ints) + tables
  int nblkZ = (nzero + 255) / 256;
  int nblkT = (T + 255) / 256;
  int nblkD = (total_cells/4 + 255) / 256;  // 6144

  k_zero   <<<nblkZ, 256, 0, stream>>>((int*)ws, nzero);
  k_targets<<<nblkT, 256, 0, stream>>>(targets, T, G, stride, ocell, keyarr,
                                       A_key, A_val, B_key, B_bits, B_maxt);
  k_sparse <<<nblkT, 256, 0, stream>>>(x, targets, T, G, stride, ocell, keyarr,
                                       A_key, A_val, B_key, B_bits, B_maxt, sums);
  k_dense  <<<nblkD, 256, 0, stream>>>(x, out, sums, G, stride, total_cells);
  k_final  <<<1, 64, 0, stream>>>(sums, out + (size_t)total_cells*5, (double)total_cells);
}